// Round 9
// baseline (91.770 us; speedup 1.0000x reference)
//
#include <hip/hip_runtime.h>

#define NSTEP  730
#define NGRID  2000
#define PRECSf 1e-5f

#define GLOBAL_AS __attribute__((address_space(1)))
#define LDS_AS    __attribute__((address_space(3)))

__device__ __forceinline__ float fast_exp2(float v) { return __builtin_amdgcn_exp2f(v); }
__device__ __forceinline__ float fast_log2(float v) { return __builtin_amdgcn_logf(v); }
__device__ __forceinline__ float med3(float a, float b, float c) {
    return __builtin_amdgcn_fmed3f(a, b, c);
}

struct Par {
    float TT, cfmax, cfmaxTT, cfrXcf, cfrTT, CWH;
    float beta, betaC, FC, betaet, betaetC;
    float PERC, omK0, k0uzl, omK1, K2;
};

#define MEMFENCE() asm volatile("" ::: "memory")
#define WAITV(N)   asm volatile("s_waitcnt vmcnt(" #N ")" ::: "memory")
// raw barrier: drain LDS ops only; gll prefetch stays in flight (counted WAITV)
#define BAR() do { MEMFENCE();                                                 \
    asm volatile("s_waitcnt lgkmcnt(0)" ::: "memory");                         \
    __builtin_amdgcn_s_barrier(); MEMFENCE(); } while (0)

// ---- snow step I (SP/MW recurrence); producer wave, one chunk ahead ----
template<int I>
__device__ __forceinline__ void snow1(const float4 (&xv)[16],
        float& SP, float& MW,
        float (&A)[16], float (&Ets)[16], float (&cEts)[16], const Par& c)
{
    const float Pt = xv[I].x, Tt = xv[I].y, Ex = xv[I].z;

    const float snow = (Tt < c.TT) ? Pt : 0.0f;
    const float rain = Pt - snow;
    const float mraw = fmaf(c.cfmax,   Tt, -c.cfmaxTT);
    const float rraw = fmaf(-c.cfrXcf, Tt,  c.cfrTT );
    const float SP1  = SP + snow;
    const float SP2  = med3(SP1 - mraw, 0.0f, SP1);       // exact: SP1 >= 0
    const float MW1  = MW + (SP1 - SP2);
    const float MW2  = med3(MW1 - rraw, 0.0f, MW1);
    SP = SP2 + (MW1 - MW2);
    const float tosoil = fmaxf(fmaf(-c.CWH, SP, MW2), 0.0f);
    MW = MW2 - tosoil;
    A[I]    = rain + tosoil;
    Ets[I]  = Ex;
    cEts[I] = c.betaetC + fast_log2(Ex);
}

// ---- soil+routing step I; consumer wave. Evap from SM1 (exact: z(FC)>=Et) ----
template<int I>
__device__ __forceinline__ void soil1(const float (&A)[16], const float (&Ets)[16],
        const float (&cEts)[16], float (&qbuf)[16],
        float& SM, float& SUZ, float& SLZ, const Par& c)
{
    const float Ac  = A[I];
    const float Et  = Ets[I];
    const float cEt = cEts[I];

    const float SMpA = SM + Ac;
    const float sw   = fast_exp2(fmaf(c.beta, fast_log2(SM), c.betaC));
    const float SM1  = fmaf(-Ac, sw, SMpA);
    const float SM2  = fminf(SM1, c.FC);
    const float inflow = SMpA - SM2;
    const float Ete  = fast_exp2(fmaf(c.betaet, fast_log2(SM1), cEt));
    SM = fmaxf(fmaxf(SM2 - Ete, SM2 - Et), PRECSf);

    const float SUZ1  = SUZ + inflow;
    const float PERCv = fminf(SUZ1, c.PERC);
    const float SUZ2  = SUZ1 - PERCv;
    const float SUZ3  = fminf(SUZ2, fmaf(c.omK0, SUZ2, c.k0uzl));
    const float SUZ4  = c.omK1 * SUZ3;
    SUZ = SUZ4;
    const float SLZ1 = SLZ + PERCv;
    const float Q2   = c.K2 * SLZ1;
    SLZ = SLZ1 - Q2;

    qbuf[I] = (SUZ2 - SUZ4) + Q2;
}

template<int I, int NS>
__device__ __forceinline__ void snow_pass(const float4 (&xv)[16],
        float& SP, float& MW, float (&A)[16], float (&Ets)[16], float (&cEts)[16],
        const Par& c)
{
    if constexpr (I < NS) {
        snow1<I>(xv, SP, MW, A, Ets, cEts, c);
        snow_pass<I + 1, NS>(xv, SP, MW, A, Ets, cEts, c);
    }
}

template<int I, int NS>
__device__ __forceinline__ void soil_pass(const float (&A)[16], const float (&Ets)[16],
        const float (&cEts)[16], float (&qbuf)[16],
        float& SM, float& SUZ, float& SLZ, const Par& c)
{
    if constexpr (I < NS) {
        soil1<I>(A, Ets, cEts, qbuf, SM, SUZ, SLZ, c);
        soil_pass<I + 1, NS>(A, Ets, cEts, qbuf, SM, SUZ, SLZ, c);
    }
}

#define LOAD_XV(B)                                                             \
    _Pragma("unroll")                                                          \
    for (int ii = 0; ii < 16; ++ii)                                            \
        xv[ii] = *reinterpret_cast<const float4*>(&xs[B][ii * 16 + crow * 4]); \
    asm volatile("" :: "v"(xv[0].x),  "v"(xv[1].x),  "v"(xv[2].x),             \
                       "v"(xv[3].x),  "v"(xv[4].x),  "v"(xv[5].x),             \
                       "v"(xv[6].x),  "v"(xv[7].x),  "v"(xv[8].x),             \
                       "v"(xv[9].x),  "v"(xv[10].x), "v"(xv[11].x),            \
                       "v"(xv[12].x), "v"(xv[13].x), "v"(xv[14].x),            \
                       "v"(xv[15].x))

// producer -> consumer handoff: lane-private float4 quads, conflict-free
#define AB_WRITE(BUF)                                                          \
    _Pragma("unroll")                                                          \
    for (int q = 0; q < 4; ++q) {                                              \
        ab[BUF][q    ][lane] = make_float4(A[4*q],   A[4*q+1],   A[4*q+2],   A[4*q+3]);    \
        ab[BUF][4 + q][lane] = make_float4(Ets[4*q], Ets[4*q+1], Ets[4*q+2], Ets[4*q+3]);  \
        ab[BUF][8 + q][lane] = make_float4(cEts[4*q],cEts[4*q+1],cEts[4*q+2],cEts[4*q+3]); \
    }

#define AB_READ(BUF) do {                                                      \
    _Pragma("unroll")                                                          \
    for (int j = 0; j < 12; ++j) rr[j] = ab[BUF][j][lane];                     \
    asm volatile("" :: "v"(rr[0].x), "v"(rr[1].x), "v"(rr[2].x), "v"(rr[3].x), \
                       "v"(rr[4].x), "v"(rr[5].x), "v"(rr[6].x), "v"(rr[7].x), \
                       "v"(rr[8].x), "v"(rr[9].x), "v"(rr[10].x),"v"(rr[11].x));\
    const float* rf = reinterpret_cast<const float*>(rr);                      \
    _Pragma("unroll")                                                          \
    for (int kk = 0; kk < 16; ++kk) {                                          \
        Ac[kk] = rf[kk]; Etc[kk] = rf[16 + kk]; cEtc[kk] = rf[32 + kk];        \
    }                                                                          \
} while (0)

#define QT_WRITE(BUF) do {                                                     \
    float* qrow = &qt[BUF][crow * 336 + m * 20];                               \
    *reinterpret_cast<float4*>(qrow + 0)  = make_float4(qbuf[0], qbuf[1], qbuf[2], qbuf[3]);    \
    *reinterpret_cast<float4*>(qrow + 4)  = make_float4(qbuf[4], qbuf[5], qbuf[6], qbuf[7]);    \
    *reinterpret_cast<float4*>(qrow + 8)  = make_float4(qbuf[8], qbuf[9], qbuf[10], qbuf[11]);  \
    *reinterpret_cast<float4*>(qrow + 12) = make_float4(qbuf[12], qbuf[13], qbuf[14], qbuf[15]);\
} while (0)

// transpose-reduce chunk (producer): lane (c,m) sums step-column m, stores out
#define REDUCE_OUT(BUF, T0, N) do {                                            \
    const float* qcol = &qt[BUF][crow * 336 + m];                              \
    float s0 = qcol[0*20]  + qcol[1*20];                                       \
    float s1 = qcol[2*20]  + qcol[3*20];                                       \
    float s2 = qcol[4*20]  + qcol[5*20];                                       \
    float s3 = qcol[6*20]  + qcol[7*20];                                       \
    float s4 = qcol[8*20]  + qcol[9*20];                                       \
    float s5 = qcol[10*20] + qcol[11*20];                                      \
    float s6 = qcol[12*20] + qcol[13*20];                                      \
    float s7 = qcol[14*20] + qcol[15*20];                                      \
    s0 += s1; s2 += s3; s4 += s5; s6 += s7;                                    \
    s0 += s2; s4 += s6; s0 += s4;                                              \
    if (m < (N)) out[(size_t)((T0) + m) * NGRID + g] = s0 * 0.0625f;           \
} while (0)

__global__ __launch_bounds__(128, 1)
void hbv_kernel(const float* __restrict__ x,
                const float* __restrict__ params,
                float* __restrict__ out)
{
    // 2 waves: wave0 = producer (staging, snow, reduce+store),
    //          wave1 = consumer (soil chain only). 4 cells x 16 members.
    __shared__ __align__(16) float4 ab[2][12][64];   // {A,Et,cEt} handoff, 24 KB
    __shared__ __align__(16) float  xs[2][256];      // x staging
    __shared__ __align__(16) float  qt[2][4 * 336];  // q transpose scratch

    const int tid  = threadIdx.x;
    const int wid  = tid >> 6;           // 0 producer, 1 consumer
    const int lane = tid & 63;
    const int g0   = blockIdx.x * 4;
    const int crow = lane >> 4;
    const int m    = lane & 15;
    const int g    = g0 + crow;

    // staging sources (producer)
    const float* srcb[4];
    int ioff[4];
#pragma unroll
    for (int j = 0; j < 4; ++j) {
        const int flat = j * 64 + lane;
        const int i    = flat >> 4;
        const int cc   = (flat >> 2) & 3;
        int comp       = flat & 3; if (comp == 3) comp = 0;
        srcb[j] = x + (size_t)(g0 + cc) * 3 + comp;
        ioff[j] = i;
    }

#define ISSUE(B, T0) do {                                                      \
    MEMFENCE();                                                                \
    _Pragma("unroll")                                                          \
    for (int j = 0; j < 4; ++j) {                                              \
        int stp = (T0) + ioff[j]; stp = stp < NSTEP ? stp : NSTEP - 1;         \
        const float* s_ = srcb[j] + (size_t)stp * (NGRID * 3);                 \
        __builtin_amdgcn_global_load_lds((const GLOBAL_AS unsigned*)s_,        \
            (LDS_AS unsigned*)&xs[B][j * 64], 4, 0, 0);                        \
    }                                                                          \
    MEMFENCE();                                                                \
} while (0)

    // --- parameter de-normalization (both waves; same (c,m)) ---
    const float lo[13] = {1.f,50.f,0.05f,0.01f,0.001f,0.2f,0.f,0.f,-2.5f,0.5f,0.f,0.f,0.3f};
    const float hi[13] = {6.f,1000.f,0.9f,0.5f,0.2f,1.f,10.f,100.f,2.5f,10.f,0.1f,0.2f,5.f};
    float p[13];
    const float* pg = params + ((size_t)g * 13) * 16 + m;
#pragma unroll
    for (int i = 0; i < 13; ++i) p[i] = lo[i] + pg[(size_t)i * 16] * (hi[i] - lo[i]);

    Par c;
    c.TT      = p[8];
    c.cfmax   = p[9];
    c.cfmaxTT = p[9] * p[8];
    c.cfrXcf  = p[10] * p[9];
    c.cfrTT   = c.cfrXcf * p[8];
    c.CWH     = p[11];
    c.beta    = p[0];
    c.betaC   = -p[0] * fast_log2(p[1]);
    c.FC      = p[1];
    c.betaet  = p[12];
    c.betaetC = -p[12] * fast_log2(p[5] * p[1]);
    c.PERC    = p[6];
    c.omK0    = 1.0f - p[2];
    c.k0uzl   = p[2] * p[7];
    c.omK1    = 1.0f - p[3];
    c.K2      = p[4];

    float SP = 0.001f, MW = 0.001f, SM = 0.001f, SUZ = 0.001f, SLZ = 0.001f;

    float4 xv[16];
    float  A[16], Ets[16], cEts[16];     // producer
    float4 rr[12];
    float  Ac[16], Etc[16], cEtc[16];    // consumer
    float  qbuf[16];

    // prologue: producer stages chunks 0,1; snow chunk 0 -> ab[0]
    if (wid == 0) {
        ISSUE(0, 0);
        ISSUE(1, 16);
        WAITV(4);
        LOAD_XV(0);
        snow_pass<0, 16>(xv, SP, MW, A, Ets, cEts, c);
        AB_WRITE(0);
    }
    BAR();

    // iter i: producer -> snow chunk i+1 (ab[(i+1)&1]) + reduce chunk i-1;
    //         consumer -> soil chunk i from ab[i&1], raw q -> qt[i&1].
    for (int i = 0; i < 46; ++i) {
        if (wid == 0) {
            if (i <= 43) ISSUE(i & 1, (i + 2) * 16);
            if (i <= 44) {
                // counted drain of chunk-(i+1) gll: newer ops =
                //  i>=2: 16 stores (iter i-1) + 4 gll (this iter) = 20
                //  i==44: 16 stores only (no new gll); i<2: 4 gll only
                if (i == 44)      { WAITV(16); }
                else if (i >= 2)  { WAITV(20); }
                else              { WAITV(4);  }
                LOAD_XV((i + 1) & 1);
                snow_pass<0, 16>(xv, SP, MW, A, Ets, cEts, c);
                AB_WRITE((i + 1) & 1);
            }
            if (i >= 1) REDUCE_OUT((i - 1) & 1, (i - 1) * 16, 16);
        } else {
            AB_READ(i & 1);
            if (i < 45) soil_pass<0, 16>(Ac, Etc, cEtc, qbuf, SM, SUZ, SLZ, c);
            else        soil_pass<0, 10>(Ac, Etc, cEtc, qbuf, SM, SUZ, SLZ, c);
            QT_WRITE(i & 1);
        }
        BAR();
    }
    // chunk 45 (steps 720..729) reduce+store
    if (wid == 0) REDUCE_OUT(1, 720, 10);
#undef ISSUE
}

extern "C" void kernel_launch(void* const* d_in, const int* in_sizes, int n_in,
                              void* d_out, int out_size, void* d_ws, size_t ws_size,
                              hipStream_t stream)
{
    const float* x      = (const float*)d_in[0];
    const float* params = (const float*)d_in[1];
    float* out          = (float*)d_out;

    hipLaunchKernelGGL(hbv_kernel, dim3(500), dim3(128), 0, stream, x, params, out);
}